// Round 6
// baseline (360.433 us; speedup 1.0000x reference)
//
#include <hip/hip_runtime.h>
#include <hip/hip_bf16.h>

#define EMB 16
#define EPT 8   // edges per 16-lane group (ILP batch)

// ---------------------------------------------------------------------------
// Kernel 1: both node transforms in one launch.
//   n < NL : TL[n] = left[n] @ Wl.T + bl
//   else   : TR[n-NL] = right[n-NL] @ Wr.T
// ---------------------------------------------------------------------------
__global__ __launch_bounds__(256) void node_transform2_kernel(
    const float* __restrict__ left, const float* __restrict__ right,
    const float* __restrict__ Wl, const float* __restrict__ bl,
    const float* __restrict__ Wr,
    float* __restrict__ TL, float* __restrict__ TR, int NL, int NR) {
    __shared__ float sWl[EMB * EMB], sWr[EMB * EMB], sbl[EMB];
    if (threadIdx.x < EMB * EMB) {
        sWl[threadIdx.x] = Wl[threadIdx.x];
        sWr[threadIdx.x] = Wr[threadIdx.x];
    }
    if (threadIdx.x < EMB) sbl[threadIdx.x] = bl[threadIdx.x];
    __syncthreads();

    int n = blockIdx.x * blockDim.x + threadIdx.x;
    if (n >= NL + NR) return;
    bool is_left = (n < NL);
    const float* X = is_left ? (left + (size_t)n * EMB)
                             : (right + (size_t)(n - NL) * EMB);
    float* Y = is_left ? (TL + (size_t)n * EMB)
                       : (TR + (size_t)(n - NL) * EMB);
    const float* sW = is_left ? sWl : sWr;

    float x[EMB];
    const float4* xp = (const float4*)X;
    float4 x0 = xp[0], x1 = xp[1], x2 = xp[2], x3 = xp[3];
    x[0] = x0.x; x[1] = x0.y; x[2] = x0.z; x[3] = x0.w;
    x[4] = x1.x; x[5] = x1.y; x[6] = x1.z; x[7] = x1.w;
    x[8] = x2.x; x[9] = x2.y; x[10] = x2.z; x[11] = x2.w;
    x[12] = x3.x; x[13] = x3.y; x[14] = x3.z; x[15] = x3.w;

    float y[EMB];
#pragma unroll
    for (int j = 0; j < EMB; ++j) {
        float a = is_left ? sbl[j] : 0.0f;
#pragma unroll
        for (int k = 0; k < EMB; ++k) a = fmaf(sW[j * EMB + k], x[k], a);
        y[j] = a;
    }

    float4* yp = (float4*)Y;
    yp[0] = make_float4(y[0], y[1], y[2], y[3]);
    yp[1] = make_float4(y[4], y[5], y[6], y[7]);
    yp[2] = make_float4(y[8], y[9], y[10], y[11]);
    yp[3] = make_float4(y[12], y[13], y[14], y[15]);
}

// ---------------------------------------------------------------------------
// Kernel 2: per-edge fused message + scatter, EPT edges per 16-lane group.
// Grid-strided edge assignment (e_j = g + j*G) keeps idx/ef loads coalesced
// across groups for each j; all 2*EPT 64B gathers are issued before any
// compute to maximize outstanding loads per wave (R5 proved latency-bound:
// EPT 1->4 took 334->206 us at constant traffic).
//   pre_t = TL[l][t] + TR[r][t] + ef*wedge[t]   (b_left folded into TL)
//   w_t   = bf[t] + sum_k Wf[t][k] * relu(pre)_k   (ds_swizzle broadcast)
//   atomicAdd(S[r][t], w_t)   -- S is directly the aggregated message.
// No early return: all 64 lanes stay active so ds_swizzle sees full groups;
// invalid batch slots clamp their loads to e=0 and skip only the atomic.
// ---------------------------------------------------------------------------
__global__ __launch_bounds__(256) void edge_scatter_kernel(
    const int* __restrict__ idx, const float* __restrict__ ef,
    const float* __restrict__ TL, const float* __restrict__ TR,
    const float* __restrict__ wedge, const float* __restrict__ Wf,
    const float* __restrict__ bf, float* __restrict__ S, int E, int G) {
    int gid = blockIdx.x * blockDim.x + threadIdx.x;
    int g = gid >> 4;
    int t = gid & 15;

    // Per-lane constants (L1-resident after first wave)
    float we = wedge[t];
    float bft = bf[t];
    float wrow[EMB];
    {
        const float4* wp = (const float4*)(Wf + t * EMB);
        float4 w0 = wp[0], w1 = wp[1], w2 = wp[2], w3 = wp[3];
        wrow[0] = w0.x; wrow[1] = w0.y; wrow[2] = w0.z; wrow[3] = w0.w;
        wrow[4] = w1.x; wrow[5] = w1.y; wrow[6] = w1.z; wrow[7] = w1.w;
        wrow[8] = w2.x; wrow[9] = w2.y; wrow[10] = w2.z; wrow[11] = w2.w;
        wrow[12] = w3.x; wrow[13] = w3.y; wrow[14] = w3.z; wrow[15] = w3.w;
    }

    int l[EPT], r[EPT];
    float efv[EPT];
    bool valid[EPT];
#pragma unroll
    for (int j = 0; j < EPT; ++j) {
        int e = g + j * G;
        valid[j] = (e < E);
        int ec = valid[j] ? e : 0;
        l[j] = idx[ec];
        r[j] = idx[E + ec];
        efv[j] = ef[ec];
    }

    float av[EPT], bv[EPT];
#pragma unroll
    for (int j = 0; j < EPT; ++j) {
        av[j] = TL[(size_t)l[j] * EMB + t];
        bv[j] = TR[(size_t)r[j] * EMB + t];
    }

#pragma unroll
    for (int j = 0; j < EPT; ++j) {
        float v = fmaxf(av[j] + bv[j] + efv[j] * we, 0.0f);
        int vi = __float_as_int(v);
        float w = bft;
#define SWIZ_STEP(K)                                                          \
        {                                                                     \
            float vk = __int_as_float(                                        \
                __builtin_amdgcn_ds_swizzle(vi, ((K) << 5) | 0x10));          \
            w = fmaf(wrow[K], vk, w);                                         \
        }
        SWIZ_STEP(0)  SWIZ_STEP(1)  SWIZ_STEP(2)  SWIZ_STEP(3)
        SWIZ_STEP(4)  SWIZ_STEP(5)  SWIZ_STEP(6)  SWIZ_STEP(7)
        SWIZ_STEP(8)  SWIZ_STEP(9)  SWIZ_STEP(10) SWIZ_STEP(11)
        SWIZ_STEP(12) SWIZ_STEP(13) SWIZ_STEP(14) SWIZ_STEP(15)
#undef SWIZ_STEP
        if (valid[j]) atomicAdd(S + (size_t)r[j] * EMB + t, w);
    }
}

// ---------------------------------------------------------------------------
// Kernel 3: per-right-node epilogue. S is already the aggregated message.
// ---------------------------------------------------------------------------
__global__ __launch_bounds__(256) void epilogue_kernel(
    const float* __restrict__ S, const float* __restrict__ right,
    const float* __restrict__ Wp, const float* __restrict__ bp,
    const float* __restrict__ Wo1, const float* __restrict__ bo1,
    const float* __restrict__ Wo2, const float* __restrict__ bo2,
    float* __restrict__ out, int N) {
    __shared__ float sWp[256], sWo2[256], sWo1[512];
    __shared__ float sbp[16], sbo1[16], sbo2[16];
    for (int i = threadIdx.x; i < 256; i += blockDim.x) {
        sWp[i] = Wp[i]; sWo2[i] = Wo2[i];
    }
    for (int i = threadIdx.x; i < 512; i += blockDim.x) sWo1[i] = Wo1[i];
    if (threadIdx.x < 16) {
        sbp[threadIdx.x] = bp[threadIdx.x];
        sbo1[threadIdx.x] = bo1[threadIdx.x];
        sbo2[threadIdx.x] = bo2[threadIdx.x];
    }
    __syncthreads();

    int n = blockIdx.x * blockDim.x + threadIdx.x;
    if (n >= N) return;

    float ra[EMB];
    {
        const float4* sp = (const float4*)(S + (size_t)n * EMB);
        float4 a0 = sp[0], a1 = sp[1], a2 = sp[2], a3 = sp[3];
        ra[0] = fmaxf(a0.x, 0.0f); ra[1] = fmaxf(a0.y, 0.0f);
        ra[2] = fmaxf(a0.z, 0.0f); ra[3] = fmaxf(a0.w, 0.0f);
        ra[4] = fmaxf(a1.x, 0.0f); ra[5] = fmaxf(a1.y, 0.0f);
        ra[6] = fmaxf(a1.z, 0.0f); ra[7] = fmaxf(a1.w, 0.0f);
        ra[8] = fmaxf(a2.x, 0.0f); ra[9] = fmaxf(a2.y, 0.0f);
        ra[10] = fmaxf(a2.z, 0.0f); ra[11] = fmaxf(a2.w, 0.0f);
        ra[12] = fmaxf(a3.x, 0.0f); ra[13] = fmaxf(a3.y, 0.0f);
        ra[14] = fmaxf(a3.z, 0.0f); ra[15] = fmaxf(a3.w, 0.0f);
    }

    float p[EMB];
#pragma unroll
    for (int j = 0; j < EMB; ++j) {
        float a = sbp[j];
#pragma unroll
        for (int k = 0; k < EMB; ++k) a = fmaf(sWp[j * EMB + k], ra[k], a);
        p[j] = a;
    }

    float rf[EMB];
    {
        const float4* rp = (const float4*)(right + (size_t)n * EMB);
        float4 a0 = rp[0], a1 = rp[1], a2 = rp[2], a3 = rp[3];
        rf[0] = a0.x; rf[1] = a0.y; rf[2] = a0.z; rf[3] = a0.w;
        rf[4] = a1.x; rf[5] = a1.y; rf[6] = a1.z; rf[7] = a1.w;
        rf[8] = a2.x; rf[9] = a2.y; rf[10] = a2.z; rf[11] = a2.w;
        rf[12] = a3.x; rf[13] = a3.y; rf[14] = a3.z; rf[15] = a3.w;
    }

    float h[EMB];
#pragma unroll
    for (int j = 0; j < EMB; ++j) {
        float a = sbo1[j];
#pragma unroll
        for (int k = 0; k < EMB; ++k) a = fmaf(sWo1[j * 32 + k], p[k], a);
#pragma unroll
        for (int k = 0; k < EMB; ++k) a = fmaf(sWo1[j * 32 + 16 + k], rf[k], a);
        h[j] = fmaxf(a, 0.0f);
    }

    float o[EMB];
#pragma unroll
    for (int j = 0; j < EMB; ++j) {
        float a = sbo2[j];
#pragma unroll
        for (int k = 0; k < EMB; ++k) a = fmaf(sWo2[j * EMB + k], h[k], a);
        o[j] = a;
    }

    float4* op = (float4*)(out + (size_t)n * EMB);
    op[0] = make_float4(o[0], o[1], o[2], o[3]);
    op[1] = make_float4(o[4], o[5], o[6], o[7]);
    op[2] = make_float4(o[8], o[9], o[10], o[11]);
    op[3] = make_float4(o[12], o[13], o[14], o[15]);
}

// ---------------------------------------------------------------------------
extern "C" void kernel_launch(void* const* d_in, const int* in_sizes, int n_in,
                              void* d_out, int out_size, void* d_ws, size_t ws_size,
                              hipStream_t stream) {
    const float* left  = (const float*)d_in[0];
    const float* ef    = (const float*)d_in[1];
    const float* right = (const float*)d_in[2];
    const int*   eidx  = (const int*)d_in[3];
    const float* W_left  = (const float*)d_in[4];
    const float* b_left  = (const float*)d_in[5];
    const float* W_edge  = (const float*)d_in[6];
    const float* W_right = (const float*)d_in[7];
    const float* W_final = (const float*)d_in[8];
    const float* b_final = (const float*)d_in[9];
    const float* W_post  = (const float*)d_in[10];
    const float* b_post  = (const float*)d_in[11];
    const float* W_out1  = (const float*)d_in[12];
    const float* b_out1  = (const float*)d_in[13];
    const float* W_out2  = (const float*)d_in[14];
    const float* b_out2  = (const float*)d_in[15];

    const int NL = in_sizes[0] / EMB;
    const int NR = in_sizes[2] / EMB;
    const int E  = in_sizes[1];

    size_t tl_b = (size_t)NL * EMB * 4;
    size_t tr_b = (size_t)NR * EMB * 4;
    char* ws = (char*)d_ws;
    float* TL = (float*)ws;
    float* TR = (float*)(ws + tl_b);
    float* S  = (float*)(ws + tl_b + tr_b);

    // Zero the scatter accumulator (ws is re-poisoned before every launch)
    (void)hipMemsetAsync(S, 0, (size_t)NR * EMB * 4, stream);

    // Both node transforms in one launch (b_left folded into TL)
    node_transform2_kernel<<<(NL + NR + 255) / 256, 256, 0, stream>>>(
        left, right, W_left, b_left, W_right, TL, TR, NL, NR);

    // Edge scatter: EPT edges per 16-lane group
    {
        int G = (E + EPT - 1) / EPT;             // number of 16-lane groups
        long long threads = (long long)G * 16;
        int blocks = (int)((threads + 255) / 256);
        edge_scatter_kernel<<<blocks, 256, 0, stream>>>(
            eidx, ef, TL, TR, W_edge, W_final, b_final, S, E, G);
    }

    // Epilogue
    epilogue_kernel<<<(NR + 255) / 256, 256, 0, stream>>>(
        S, right, W_post, b_post, W_out1, b_out1, W_out2, b_out2,
        (float*)d_out, NR);
}

// Round 7
// 354.902 us; speedup vs baseline: 1.0156x; 1.0156x over previous
//
#include <hip/hip_runtime.h>
#include <hip/hip_bf16.h>

#define EMB 16
#define EPT 4   // edges per 16-lane group (ILP batch)

typedef _Float16 half8 __attribute__((ext_vector_type(8)));

// ---------------------------------------------------------------------------
// Kernel 1: both node transforms in one launch; outputs fp16 tables.
//   n < NL : TL[n] = fp16(left[n] @ Wl.T + bl)
//   else   : TR[n-NL] = fp16(right[n-NL] @ Wr.T)
// fp16 tables halve the per-edge gather sector (64B -> 32B) and halve the
// random-gather working set (25.6 -> 12.8 MB -> better per-XCD L2 hit rate).
// fp16 mantissa (10b) keeps quantization ~5e-4 relative — well within the
// 0.13 absmax budget (f32 path measured 0.0156).
// ---------------------------------------------------------------------------
__global__ __launch_bounds__(256) void node_transform2_kernel(
    const float* __restrict__ left, const float* __restrict__ right,
    const float* __restrict__ Wl, const float* __restrict__ bl,
    const float* __restrict__ Wr,
    _Float16* __restrict__ TL, _Float16* __restrict__ TR, int NL, int NR) {
    __shared__ float sWl[EMB * EMB], sWr[EMB * EMB], sbl[EMB];
    if (threadIdx.x < EMB * EMB) {
        sWl[threadIdx.x] = Wl[threadIdx.x];
        sWr[threadIdx.x] = Wr[threadIdx.x];
    }
    if (threadIdx.x < EMB) sbl[threadIdx.x] = bl[threadIdx.x];
    __syncthreads();

    int n = blockIdx.x * blockDim.x + threadIdx.x;
    if (n >= NL + NR) return;
    bool is_left = (n < NL);
    const float* X = is_left ? (left + (size_t)n * EMB)
                             : (right + (size_t)(n - NL) * EMB);
    _Float16* Y = is_left ? (TL + (size_t)n * EMB)
                          : (TR + (size_t)(n - NL) * EMB);
    const float* sW = is_left ? sWl : sWr;

    float x[EMB];
    const float4* xp = (const float4*)X;
    float4 x0 = xp[0], x1 = xp[1], x2 = xp[2], x3 = xp[3];
    x[0] = x0.x; x[1] = x0.y; x[2] = x0.z; x[3] = x0.w;
    x[4] = x1.x; x[5] = x1.y; x[6] = x1.z; x[7] = x1.w;
    x[8] = x2.x; x[9] = x2.y; x[10] = x2.z; x[11] = x2.w;
    x[12] = x3.x; x[13] = x3.y; x[14] = x3.z; x[15] = x3.w;

    float y[EMB];
#pragma unroll
    for (int j = 0; j < EMB; ++j) {
        float a = is_left ? sbl[j] : 0.0f;
#pragma unroll
        for (int k = 0; k < EMB; ++k) a = fmaf(sW[j * EMB + k], x[k], a);
        y[j] = a;
    }

    half8* yp = (half8*)Y;
    half8 h0, h1;
#pragma unroll
    for (int k = 0; k < 8; ++k) h0[k] = (_Float16)y[k];
#pragma unroll
    for (int k = 0; k < 8; ++k) h1[k] = (_Float16)y[8 + k];
    yp[0] = h0;
    yp[1] = h1;
}

// ---------------------------------------------------------------------------
// Kernel 2: per-edge fused message + scatter, EPT edges per 16-lane group.
// Grid-strided edge assignment (e_j = g + j*G) keeps idx/ef loads coalesced;
// all 2*EPT gathers (now 32B fp16 sectors) are issued before any compute
// (R5 proved latency sensitivity; R6 proved concurrency is saturated — the
// remaining lever is bytes, hence fp16 tables).
//   pre_t = TL[l][t] + TR[r][t] + ef*wedge[t]   (b_left folded into TL)
//   w_t   = bf[t] + sum_k Wf[t][k] * relu(pre)_k   (ds_swizzle broadcast)
//   atomicAdd(S[r][t], w_t)   -- S is directly the aggregated message.
// ---------------------------------------------------------------------------
__global__ __launch_bounds__(256) void edge_scatter_kernel(
    const int* __restrict__ idx, const float* __restrict__ ef,
    const _Float16* __restrict__ TL, const _Float16* __restrict__ TR,
    const float* __restrict__ wedge, const float* __restrict__ Wf,
    const float* __restrict__ bf, float* __restrict__ S, int E, int G) {
    int gid = blockIdx.x * blockDim.x + threadIdx.x;
    int g = gid >> 4;
    int t = gid & 15;

    // Per-lane constants (L1-resident after first wave)
    float we = wedge[t];
    float bft = bf[t];
    float wrow[EMB];
    {
        const float4* wp = (const float4*)(Wf + t * EMB);
        float4 w0 = wp[0], w1 = wp[1], w2 = wp[2], w3 = wp[3];
        wrow[0] = w0.x; wrow[1] = w0.y; wrow[2] = w0.z; wrow[3] = w0.w;
        wrow[4] = w1.x; wrow[5] = w1.y; wrow[6] = w1.z; wrow[7] = w1.w;
        wrow[8] = w2.x; wrow[9] = w2.y; wrow[10] = w2.z; wrow[11] = w2.w;
        wrow[12] = w3.x; wrow[13] = w3.y; wrow[14] = w3.z; wrow[15] = w3.w;
    }

    int l[EPT], r[EPT];
    float efv[EPT];
    bool valid[EPT];
#pragma unroll
    for (int j = 0; j < EPT; ++j) {
        int e = g + j * G;
        valid[j] = (e < E);
        int ec = valid[j] ? e : 0;
        l[j] = idx[ec];
        r[j] = idx[E + ec];
        efv[j] = ef[ec];
    }

    _Float16 ah[EPT], bh[EPT];
#pragma unroll
    for (int j = 0; j < EPT; ++j) {
        ah[j] = TL[(size_t)l[j] * EMB + t];
        bh[j] = TR[(size_t)r[j] * EMB + t];
    }

#pragma unroll
    for (int j = 0; j < EPT; ++j) {
        float v = fmaxf((float)ah[j] + (float)bh[j] + efv[j] * we, 0.0f);
        int vi = __float_as_int(v);
        float w = bft;
#define SWIZ_STEP(K)                                                          \
        {                                                                     \
            float vk = __int_as_float(                                        \
                __builtin_amdgcn_ds_swizzle(vi, ((K) << 5) | 0x10));          \
            w = fmaf(wrow[K], vk, w);                                         \
        }
        SWIZ_STEP(0)  SWIZ_STEP(1)  SWIZ_STEP(2)  SWIZ_STEP(3)
        SWIZ_STEP(4)  SWIZ_STEP(5)  SWIZ_STEP(6)  SWIZ_STEP(7)
        SWIZ_STEP(8)  SWIZ_STEP(9)  SWIZ_STEP(10) SWIZ_STEP(11)
        SWIZ_STEP(12) SWIZ_STEP(13) SWIZ_STEP(14) SWIZ_STEP(15)
#undef SWIZ_STEP
        if (valid[j]) atomicAdd(S + (size_t)r[j] * EMB + t, w);
    }
}

// ---------------------------------------------------------------------------
// Kernel 3: per-right-node epilogue. S is already the aggregated message.
// ---------------------------------------------------------------------------
__global__ __launch_bounds__(256) void epilogue_kernel(
    const float* __restrict__ S, const float* __restrict__ right,
    const float* __restrict__ Wp, const float* __restrict__ bp,
    const float* __restrict__ Wo1, const float* __restrict__ bo1,
    const float* __restrict__ Wo2, const float* __restrict__ bo2,
    float* __restrict__ out, int N) {
    __shared__ float sWp[256], sWo2[256], sWo1[512];
    __shared__ float sbp[16], sbo1[16], sbo2[16];
    for (int i = threadIdx.x; i < 256; i += blockDim.x) {
        sWp[i] = Wp[i]; sWo2[i] = Wo2[i];
    }
    for (int i = threadIdx.x; i < 512; i += blockDim.x) sWo1[i] = Wo1[i];
    if (threadIdx.x < 16) {
        sbp[threadIdx.x] = bp[threadIdx.x];
        sbo1[threadIdx.x] = bo1[threadIdx.x];
        sbo2[threadIdx.x] = bo2[threadIdx.x];
    }
    __syncthreads();

    int n = blockIdx.x * blockDim.x + threadIdx.x;
    if (n >= N) return;

    float ra[EMB];
    {
        const float4* sp = (const float4*)(S + (size_t)n * EMB);
        float4 a0 = sp[0], a1 = sp[1], a2 = sp[2], a3 = sp[3];
        ra[0] = fmaxf(a0.x, 0.0f); ra[1] = fmaxf(a0.y, 0.0f);
        ra[2] = fmaxf(a0.z, 0.0f); ra[3] = fmaxf(a0.w, 0.0f);
        ra[4] = fmaxf(a1.x, 0.0f); ra[5] = fmaxf(a1.y, 0.0f);
        ra[6] = fmaxf(a1.z, 0.0f); ra[7] = fmaxf(a1.w, 0.0f);
        ra[8] = fmaxf(a2.x, 0.0f); ra[9] = fmaxf(a2.y, 0.0f);
        ra[10] = fmaxf(a2.z, 0.0f); ra[11] = fmaxf(a2.w, 0.0f);
        ra[12] = fmaxf(a3.x, 0.0f); ra[13] = fmaxf(a3.y, 0.0f);
        ra[14] = fmaxf(a3.z, 0.0f); ra[15] = fmaxf(a3.w, 0.0f);
    }

    float p[EMB];
#pragma unroll
    for (int j = 0; j < EMB; ++j) {
        float a = sbp[j];
#pragma unroll
        for (int k = 0; k < EMB; ++k) a = fmaf(sWp[j * EMB + k], ra[k], a);
        p[j] = a;
    }

    float rf[EMB];
    {
        const float4* rp = (const float4*)(right + (size_t)n * EMB);
        float4 a0 = rp[0], a1 = rp[1], a2 = rp[2], a3 = rp[3];
        rf[0] = a0.x; rf[1] = a0.y; rf[2] = a0.z; rf[3] = a0.w;
        rf[4] = a1.x; rf[5] = a1.y; rf[6] = a1.z; rf[7] = a1.w;
        rf[8] = a2.x; rf[9] = a2.y; rf[10] = a2.z; rf[11] = a2.w;
        rf[12] = a3.x; rf[13] = a3.y; rf[14] = a3.z; rf[15] = a3.w;
    }

    float h[EMB];
#pragma unroll
    for (int j = 0; j < EMB; ++j) {
        float a = sbo1[j];
#pragma unroll
        for (int k = 0; k < EMB; ++k) a = fmaf(sWo1[j * 32 + k], p[k], a);
#pragma unroll
        for (int k = 0; k < EMB; ++k) a = fmaf(sWo1[j * 32 + 16 + k], rf[k], a);
        h[j] = fmaxf(a, 0.0f);
    }

    float o[EMB];
#pragma unroll
    for (int j = 0; j < EMB; ++j) {
        float a = sbo2[j];
#pragma unroll
        for (int k = 0; k < EMB; ++k) a = fmaf(sWo2[j * EMB + k], h[k], a);
        o[j] = a;
    }

    float4* op = (float4*)(out + (size_t)n * EMB);
    op[0] = make_float4(o[0], o[1], o[2], o[3]);
    op[1] = make_float4(o[4], o[5], o[6], o[7]);
    op[2] = make_float4(o[8], o[9], o[10], o[11]);
    op[3] = make_float4(o[12], o[13], o[14], o[15]);
}

// ---------------------------------------------------------------------------
extern "C" void kernel_launch(void* const* d_in, const int* in_sizes, int n_in,
                              void* d_out, int out_size, void* d_ws, size_t ws_size,
                              hipStream_t stream) {
    const float* left  = (const float*)d_in[0];
    const float* ef    = (const float*)d_in[1];
    const float* right = (const float*)d_in[2];
    const int*   eidx  = (const int*)d_in[3];
    const float* W_left  = (const float*)d_in[4];
    const float* b_left  = (const float*)d_in[5];
    const float* W_edge  = (const float*)d_in[6];
    const float* W_right = (const float*)d_in[7];
    const float* W_final = (const float*)d_in[8];
    const float* b_final = (const float*)d_in[9];
    const float* W_post  = (const float*)d_in[10];
    const float* b_post  = (const float*)d_in[11];
    const float* W_out1  = (const float*)d_in[12];
    const float* b_out1  = (const float*)d_in[13];
    const float* W_out2  = (const float*)d_in[14];
    const float* b_out2  = (const float*)d_in[15];

    const int NL = in_sizes[0] / EMB;
    const int NR = in_sizes[2] / EMB;
    const int E  = in_sizes[1];

    // Workspace: TL16 | TR16 | S (f32)
    size_t tl_b = (size_t)NL * EMB * 2;
    size_t tr_b = (size_t)NR * EMB * 2;
    char* ws = (char*)d_ws;
    _Float16* TL = (_Float16*)ws;
    _Float16* TR = (_Float16*)(ws + tl_b);
    float* S = (float*)(ws + tl_b + tr_b);

    // Zero the scatter accumulator (ws is re-poisoned before every launch)
    (void)hipMemsetAsync(S, 0, (size_t)NR * EMB * 4, stream);

    // Both node transforms in one launch (b_left folded into TL)
    node_transform2_kernel<<<(NL + NR + 255) / 256, 256, 0, stream>>>(
        left, right, W_left, b_left, W_right, TL, TR, NL, NR);

    // Edge scatter: EPT edges per 16-lane group
    {
        int G = (E + EPT - 1) / EPT;             // number of 16-lane groups
        long long threads = (long long)G * 16;
        int blocks = (int)((threads + 255) / 256);
        edge_scatter_kernel<<<blocks, 256, 0, stream>>>(
            eidx, ef, TL, TR, W_edge, W_final, b_final, S, E, G);
    }

    // Epilogue
    epilogue_kernel<<<(NR + 255) / 256, 256, 0, stream>>>(
        S, right, W_post, b_post, W_out1, b_out1, W_out2, b_out2,
        (float*)d_out, NR);
}

// Round 8
// 353.323 us; speedup vs baseline: 1.0201x; 1.0045x over previous
//
#include <hip/hip_runtime.h>
#include <hip/hip_bf16.h>
#include <hip/hip_fp16.h>

#define EMB 16
#define EPT 4   // edges per 16-lane group (ILP batch)

typedef _Float16 half8 __attribute__((ext_vector_type(8)));

// ---------------------------------------------------------------------------
// Kernel 1: both node transforms in one launch; outputs fp16 tables.
//   n < NL : TL[n] = fp16(left[n] @ Wl.T + bl)
//   else   : TR[n-NL] = fp16(right[n-NL] @ Wr.T)
// ---------------------------------------------------------------------------
__global__ __launch_bounds__(256) void node_transform2_kernel(
    const float* __restrict__ left, const float* __restrict__ right,
    const float* __restrict__ Wl, const float* __restrict__ bl,
    const float* __restrict__ Wr,
    _Float16* __restrict__ TL, _Float16* __restrict__ TR, int NL, int NR) {
    __shared__ float sWl[EMB * EMB], sWr[EMB * EMB], sbl[EMB];
    if (threadIdx.x < EMB * EMB) {
        sWl[threadIdx.x] = Wl[threadIdx.x];
        sWr[threadIdx.x] = Wr[threadIdx.x];
    }
    if (threadIdx.x < EMB) sbl[threadIdx.x] = bl[threadIdx.x];
    __syncthreads();

    int n = blockIdx.x * blockDim.x + threadIdx.x;
    if (n >= NL + NR) return;
    bool is_left = (n < NL);
    const float* X = is_left ? (left + (size_t)n * EMB)
                             : (right + (size_t)(n - NL) * EMB);
    _Float16* Y = is_left ? (TL + (size_t)n * EMB)
                          : (TR + (size_t)(n - NL) * EMB);
    const float* sW = is_left ? sWl : sWr;

    float x[EMB];
    const float4* xp = (const float4*)X;
    float4 x0 = xp[0], x1 = xp[1], x2 = xp[2], x3 = xp[3];
    x[0] = x0.x; x[1] = x0.y; x[2] = x0.z; x[3] = x0.w;
    x[4] = x1.x; x[5] = x1.y; x[6] = x1.z; x[7] = x1.w;
    x[8] = x2.x; x[9] = x2.y; x[10] = x2.z; x[11] = x2.w;
    x[12] = x3.x; x[13] = x3.y; x[14] = x3.z; x[15] = x3.w;

    float y[EMB];
#pragma unroll
    for (int j = 0; j < EMB; ++j) {
        float a = is_left ? sbl[j] : 0.0f;
#pragma unroll
        for (int k = 0; k < EMB; ++k) a = fmaf(sW[j * EMB + k], x[k], a);
        y[j] = a;
    }

    half8* yp = (half8*)Y;
    half8 h0, h1;
#pragma unroll
    for (int k = 0; k < 8; ++k) h0[k] = (_Float16)y[k];
#pragma unroll
    for (int k = 0; k < 8; ++k) h1[k] = (_Float16)y[8 + k];
    yp[0] = h0;
    yp[1] = h1;
}

// ---------------------------------------------------------------------------
// Kernel 2: per-edge fused message + scatter, EPT edges per 16-lane group.
// R5: latency-bound -> batch; R6: concurrency saturated; R7: gather bytes
// don't matter. Remaining lever: atomic granule. The per-edge f32 atomic
// (16 lanes x 4B = 64B) becomes a packed-fp16 atomic (8 lanes x __half2 =
// 32B) via global_atomic_pk_add_f16 — halving RMW granules/bytes at the
// memory-side coherence point.
//   pre_t = TL[l][t] + TR[r][t] + ef*wedge[t]   (b_left folded into TL)
//   w_t   = bf[t] + sum_k Wf[t][k] * relu(pre)_k   (ds_swizzle broadcast)
// Lane j<8 packs (w_{2j}, w_{2j+1}) via ds_bpermute and issues the pk atomic.
// ---------------------------------------------------------------------------
__global__ __launch_bounds__(256) void edge_scatter_kernel(
    const int* __restrict__ idx, const float* __restrict__ ef,
    const _Float16* __restrict__ TL, const _Float16* __restrict__ TR,
    const float* __restrict__ wedge, const float* __restrict__ Wf,
    const float* __restrict__ bf, __half2* __restrict__ S, int E, int G) {
    int gid = blockIdx.x * blockDim.x + threadIdx.x;
    int g = gid >> 4;
    int t = gid & 15;

    int lane = threadIdx.x & 63;
    int gbase = lane & 48;                       // 16-lane group base in wave
    int bp0 = (gbase | ((2 * t) & 15)) << 2;     // byte addr for ds_bpermute
    int bp1 = (gbase | ((2 * t + 1) & 15)) << 2;

    // Per-lane constants (L1-resident after first wave)
    float we = wedge[t];
    float bft = bf[t];
    float wrow[EMB];
    {
        const float4* wp = (const float4*)(Wf + t * EMB);
        float4 w0 = wp[0], w1 = wp[1], w2 = wp[2], w3 = wp[3];
        wrow[0] = w0.x; wrow[1] = w0.y; wrow[2] = w0.z; wrow[3] = w0.w;
        wrow[4] = w1.x; wrow[5] = w1.y; wrow[6] = w1.z; wrow[7] = w1.w;
        wrow[8] = w2.x; wrow[9] = w2.y; wrow[10] = w2.z; wrow[11] = w2.w;
        wrow[12] = w3.x; wrow[13] = w3.y; wrow[14] = w3.z; wrow[15] = w3.w;
    }

    int l[EPT], r[EPT];
    float efv[EPT];
    bool valid[EPT];
#pragma unroll
    for (int j = 0; j < EPT; ++j) {
        int e = g + j * G;
        valid[j] = (e < E);
        int ec = valid[j] ? e : 0;
        l[j] = idx[ec];
        r[j] = idx[E + ec];
        efv[j] = ef[ec];
    }

    _Float16 ah[EPT], bh[EPT];
#pragma unroll
    for (int j = 0; j < EPT; ++j) {
        ah[j] = TL[(size_t)l[j] * EMB + t];
        bh[j] = TR[(size_t)r[j] * EMB + t];
    }

#pragma unroll
    for (int j = 0; j < EPT; ++j) {
        float v = fmaxf((float)ah[j] + (float)bh[j] + efv[j] * we, 0.0f);
        int vi = __float_as_int(v);
        float w = bft;
#define SWIZ_STEP(K)                                                          \
        {                                                                     \
            float vk = __int_as_float(                                        \
                __builtin_amdgcn_ds_swizzle(vi, ((K) << 5) | 0x10));          \
            w = fmaf(wrow[K], vk, w);                                         \
        }
        SWIZ_STEP(0)  SWIZ_STEP(1)  SWIZ_STEP(2)  SWIZ_STEP(3)
        SWIZ_STEP(4)  SWIZ_STEP(5)  SWIZ_STEP(6)  SWIZ_STEP(7)
        SWIZ_STEP(8)  SWIZ_STEP(9)  SWIZ_STEP(10) SWIZ_STEP(11)
        SWIZ_STEP(12) SWIZ_STEP(13) SWIZ_STEP(14) SWIZ_STEP(15)
#undef SWIZ_STEP

        // Pack (w_{2t}, w_{2t+1}) into lane t (t<8) and issue pk fp16 atomic.
        int wi = __float_as_int(w);
        float w0 = __int_as_float(__builtin_amdgcn_ds_bpermute(bp0, wi));
        float w1 = __int_as_float(__builtin_amdgcn_ds_bpermute(bp1, wi));
        if (valid[j] && t < 8) {
            __half2 hv = __floats2half2_rn(w0, w1);
            unsafeAtomicAdd(S + (size_t)r[j] * 8 + t, hv);
        }
    }
}

// ---------------------------------------------------------------------------
// Kernel 3: per-right-node epilogue. S (fp16) is the aggregated message.
// ---------------------------------------------------------------------------
__global__ __launch_bounds__(256) void epilogue_kernel(
    const _Float16* __restrict__ S, const float* __restrict__ right,
    const float* __restrict__ Wp, const float* __restrict__ bp,
    const float* __restrict__ Wo1, const float* __restrict__ bo1,
    const float* __restrict__ Wo2, const float* __restrict__ bo2,
    float* __restrict__ out, int N) {
    __shared__ float sWp[256], sWo2[256], sWo1[512];
    __shared__ float sbp[16], sbo1[16], sbo2[16];
    for (int i = threadIdx.x; i < 256; i += blockDim.x) {
        sWp[i] = Wp[i]; sWo2[i] = Wo2[i];
    }
    for (int i = threadIdx.x; i < 512; i += blockDim.x) sWo1[i] = Wo1[i];
    if (threadIdx.x < 16) {
        sbp[threadIdx.x] = bp[threadIdx.x];
        sbo1[threadIdx.x] = bo1[threadIdx.x];
        sbo2[threadIdx.x] = bo2[threadIdx.x];
    }
    __syncthreads();

    int n = blockIdx.x * blockDim.x + threadIdx.x;
    if (n >= N) return;

    float ra[EMB];
    {
        const half8* sp = (const half8*)(S + (size_t)n * EMB);
        half8 a0 = sp[0], a1 = sp[1];
#pragma unroll
        for (int k = 0; k < 8; ++k) ra[k] = fmaxf((float)a0[k], 0.0f);
#pragma unroll
        for (int k = 0; k < 8; ++k) ra[8 + k] = fmaxf((float)a1[k], 0.0f);
    }

    float p[EMB];
#pragma unroll
    for (int j = 0; j < EMB; ++j) {
        float a = sbp[j];
#pragma unroll
        for (int k = 0; k < EMB; ++k) a = fmaf(sWp[j * EMB + k], ra[k], a);
        p[j] = a;
    }

    float rf[EMB];
    {
        const float4* rp = (const float4*)(right + (size_t)n * EMB);
        float4 a0 = rp[0], a1 = rp[1], a2 = rp[2], a3 = rp[3];
        rf[0] = a0.x; rf[1] = a0.y; rf[2] = a0.z; rf[3] = a0.w;
        rf[4] = a1.x; rf[5] = a1.y; rf[6] = a1.z; rf[7] = a1.w;
        rf[8] = a2.x; rf[9] = a2.y; rf[10] = a2.z; rf[11] = a2.w;
        rf[12] = a3.x; rf[13] = a3.y; rf[14] = a3.z; rf[15] = a3.w;
    }

    float h[EMB];
#pragma unroll
    for (int j = 0; j < EMB; ++j) {
        float a = sbo1[j];
#pragma unroll
        for (int k = 0; k < EMB; ++k) a = fmaf(sWo1[j * 32 + k], p[k], a);
#pragma unroll
        for (int k = 0; k < EMB; ++k) a = fmaf(sWo1[j * 32 + 16 + k], rf[k], a);
        h[j] = fmaxf(a, 0.0f);
    }

    float o[EMB];
#pragma unroll
    for (int j = 0; j < EMB; ++j) {
        float a = sbo2[j];
#pragma unroll
        for (int k = 0; k < EMB; ++k) a = fmaf(sWo2[j * EMB + k], h[k], a);
        o[j] = a;
    }

    float4* op = (float4*)(out + (size_t)n * EMB);
    op[0] = make_float4(o[0], o[1], o[2], o[3]);
    op[1] = make_float4(o[4], o[5], o[6], o[7]);
    op[2] = make_float4(o[8], o[9], o[10], o[11]);
    op[3] = make_float4(o[12], o[13], o[14], o[15]);
}

// ---------------------------------------------------------------------------
extern "C" void kernel_launch(void* const* d_in, const int* in_sizes, int n_in,
                              void* d_out, int out_size, void* d_ws, size_t ws_size,
                              hipStream_t stream) {
    const float* left  = (const float*)d_in[0];
    const float* ef    = (const float*)d_in[1];
    const float* right = (const float*)d_in[2];
    const int*   eidx  = (const int*)d_in[3];
    const float* W_left  = (const float*)d_in[4];
    const float* b_left  = (const float*)d_in[5];
    const float* W_edge  = (const float*)d_in[6];
    const float* W_right = (const float*)d_in[7];
    const float* W_final = (const float*)d_in[8];
    const float* b_final = (const float*)d_in[9];
    const float* W_post  = (const float*)d_in[10];
    const float* b_post  = (const float*)d_in[11];
    const float* W_out1  = (const float*)d_in[12];
    const float* b_out1  = (const float*)d_in[13];
    const float* W_out2  = (const float*)d_in[14];
    const float* b_out2  = (const float*)d_in[15];

    const int NL = in_sizes[0] / EMB;
    const int NR = in_sizes[2] / EMB;
    const int E  = in_sizes[1];

    // Workspace: TL16 | TR16 | S (fp16)
    size_t tl_b = (size_t)NL * EMB * 2;
    size_t tr_b = (size_t)NR * EMB * 2;
    char* ws = (char*)d_ws;
    _Float16* TL = (_Float16*)ws;
    _Float16* TR = (_Float16*)(ws + tl_b);
    _Float16* S16 = (_Float16*)(ws + tl_b + tr_b);

    // Zero the scatter accumulator (ws is re-poisoned before every launch)
    (void)hipMemsetAsync(S16, 0, (size_t)NR * EMB * 2, stream);

    // Both node transforms in one launch (b_left folded into TL)
    node_transform2_kernel<<<(NL + NR + 255) / 256, 256, 0, stream>>>(
        left, right, W_left, b_left, W_right, TL, TR, NL, NR);

    // Edge scatter: EPT edges per 16-lane group, packed fp16 atomics
    {
        int G = (E + EPT - 1) / EPT;             // number of 16-lane groups
        long long threads = (long long)G * 16;
        int blocks = (int)((threads + 255) / 256);
        edge_scatter_kernel<<<blocks, 256, 0, stream>>>(
            eidx, ef, TL, TR, W_edge, W_final, b_final, (__half2*)S16, E, G);
    }

    // Epilogue
    epilogue_kernel<<<(NR + 255) / 256, 256, 0, stream>>>(
        S16, right, W_post, b_post, W_out1, b_out1, W_out2, b_out2,
        (float*)d_out, NR);
}